// Round 3
// baseline (4098.081 us; speedup 1.0000x reference)
//
#include <hip/hip_runtime.h>
#include <hip/hip_cooperative_groups.h>
#include <cstdint>
#include <cstddef>

namespace cg = cooperative_groups;

#define HID   1024
#define G4    4096
#define BB    64
#define TSEQ  128
#define NSTEP 127

typedef __attribute__((ext_vector_type(4))) float f32x4;
typedef __attribute__((ext_vector_type(8))) short bf16x8;

__device__ __forceinline__ unsigned short f2bf(float x) {
  union { float f; unsigned u; } v; v.f = x;
  unsigned r = v.u + 0x7FFF + ((v.u >> 16) & 1);   // RNE
  return (unsigned short)(r >> 16);
}

// ---------------------------------------------------------------------------
__global__ __launch_bounds__(256) void conv_f32_bf16(
    const float* __restrict__ in, unsigned short* __restrict__ out, int n)
{
  int i = (blockIdx.x * 256 + threadIdx.x) * 8;
  if (i >= n) return;
  float4 v0 = *reinterpret_cast<const float4*>(&in[i]);
  float4 v1 = *reinterpret_cast<const float4*>(&in[i + 4]);
  unsigned short u[8];
  u[0] = f2bf(v0.x); u[1] = f2bf(v0.y); u[2] = f2bf(v0.z); u[3] = f2bf(v0.w);
  u[4] = f2bf(v1.x); u[5] = f2bf(v1.y); u[6] = f2bf(v1.z); u[7] = f2bf(v1.w);
  *reinterpret_cast<bf16x8*>(&out[i]) = *reinterpret_cast<bf16x8*>(u);
}

__global__ __launch_bounds__(256) void bias_add(
    const float* __restrict__ b_ih, const float* __restrict__ b_hh,
    float* __restrict__ bias)
{
  int i = blockIdx.x * 256 + threadIdx.x;
  if (i < G4) bias[i] = b_ih[i] + b_hh[i];
}

// ---------------------------------------------------------------------------
// Gather embedding rows for steps [t0, t0+tc) -> bf16 A [Mt][HID].
// ---------------------------------------------------------------------------
__global__ __launch_bounds__(256) void conv_A(
    const int* __restrict__ tgt, const float* __restrict__ emb,
    unsigned short* __restrict__ A, int t0, int tc)
{
  int i = blockIdx.x * 256 + threadIdx.x;
  int m  = i >> 7;
  int k8 = (i & 127) * 8;
  int tl = m >> 6, b = m & 63;
  float4 v0 = make_float4(0.f, 0.f, 0.f, 0.f), v1 = v0;
  if (tl < tc) {
    int tok = tgt[b * TSEQ + t0 + tl];
    if (tok != 0) {
      const float* src = &emb[(size_t)tok * HID + k8];
      v0 = *reinterpret_cast<const float4*>(src);
      v1 = *reinterpret_cast<const float4*>(src + 4);
    }
  }
  unsigned short u[8];
  u[0] = f2bf(v0.x); u[1] = f2bf(v0.y); u[2] = f2bf(v0.z); u[3] = f2bf(v0.w);
  u[4] = f2bf(v1.x); u[5] = f2bf(v1.y); u[6] = f2bf(v1.z); u[7] = f2bf(v1.w);
  *reinterpret_cast<bf16x8*>(&A[(size_t)m * HID + k8]) = *reinterpret_cast<bf16x8*>(u);
}

// ---------------------------------------------------------------------------
// Input GEMM, bf16 MFMA 16x16x32 (unchanged from R2, verified).
// ---------------------------------------------------------------------------
__global__ __launch_bounds__(256) void gin_mfma(
    const unsigned short* __restrict__ A, const unsigned short* __restrict__ W,
    const float* __restrict__ bias, float* __restrict__ gin, int Mvalid)
{
  __shared__ unsigned short As[128 * 40];
  __shared__ unsigned short Bs[128 * 40];

  const int tid = threadIdx.x;
  const int m0 = blockIdx.x * 128, n0 = blockIdx.y * 128;
  const int l  = tid & 63, w = tid >> 6;
  const int wr = w >> 1, wc = w & 1;
  const int lr = l & 15, lh = l >> 4;

  f32x4 acc[4][4];
#pragma unroll
  for (int i = 0; i < 4; ++i)
#pragma unroll
    for (int j = 0; j < 4; ++j) acc[i][j] = (f32x4)0.f;

  for (int kc = 0; kc < HID; kc += 32) {
#pragma unroll
    for (int it = 0; it < 2; ++it) {
      int c = tid + it * 256;
      int row = c >> 2, k8 = (c & 3) * 8;
      *reinterpret_cast<bf16x8*>(&As[row * 40 + k8]) =
          *reinterpret_cast<const bf16x8*>(&A[(size_t)(m0 + row) * HID + kc + k8]);
      *reinterpret_cast<bf16x8*>(&Bs[row * 40 + k8]) =
          *reinterpret_cast<const bf16x8*>(&W[(size_t)(n0 + row) * HID + kc + k8]);
    }
    __syncthreads();

    bf16x8 af[4], bfr[4];
#pragma unroll
    for (int i = 0; i < 4; ++i) {
      af[i]  = *reinterpret_cast<const bf16x8*>(&As[(wr * 64 + i * 16 + lr) * 40 + lh * 8]);
      bfr[i] = *reinterpret_cast<const bf16x8*>(&Bs[(wc * 64 + i * 16 + lr) * 40 + lh * 8]);
    }
#pragma unroll
    for (int i = 0; i < 4; ++i)
#pragma unroll
      for (int j = 0; j < 4; ++j)
        acc[i][j] = __builtin_amdgcn_mfma_f32_16x16x32_bf16(af[i], bfr[j], acc[i][j], 0, 0, 0);
    __syncthreads();
  }

#pragma unroll
  for (int j = 0; j < 4; ++j) {
    int n = n0 + wc * 64 + j * 16 + lr;
    float bn = bias[n];
#pragma unroll
    for (int i = 0; i < 4; ++i) {
      int mb = m0 + wr * 64 + i * 16 + lh * 4;
#pragma unroll
      for (int r = 0; r < 4; ++r) {
        int m = mb + r;
        if (m < Mvalid) gin[(size_t)m * G4 + n] = acc[i][j][r] + bn;
      }
    }
  }
}

// ---------------------------------------------------------------------------
// Persistent LSTM: one cooperative launch runs tc steps, grid.sync per step.
// 256 blocks x 256 thr (4 waves). Block = (unit-group u0, batch-group b0)
// = 16 units x 16 batches. w_hh B-fragments live in VGPRs (loaded once);
// waves K-split (256 each); LDS reduce; c is thread-private in a register.
// h double-buffered bf16 in ws: hbf0 holds h_t for even t, hbf1 for odd t.
// ---------------------------------------------------------------------------
__global__ __launch_bounds__(256, 1) void lstm_persist(
    const unsigned short* __restrict__ whh, const float* __restrict__ gin,
    unsigned short* __restrict__ hbf0, unsigned short* __restrict__ hbf1,
    float* __restrict__ c_ws, const float* __restrict__ c0,
    float* __restrict__ out, int t0, int tc)
{
  cg::grid_group grid = cg::this_grid();
  __shared__ float red[4][4][16][16];   // [wave][gate][batch][unit]

  const int tid = threadIdx.x;
  const int l = tid & 63, w = tid >> 6;
  const int lr = l & 15, lh = l >> 4;
  const int bk = blockIdx.x;
  const int u0 = (bk >> 2) * 16;
  const int b0 = (bk & 3) * 16;

  // --- load this wave's w_hh B-fragments into registers (once) ---
  bf16x8 bf[4][8];
#pragma unroll
  for (int g = 0; g < 4; ++g)
#pragma unroll
    for (int kk = 0; kk < 8; ++kk)
      bf[g][kk] = *reinterpret_cast<const bf16x8*>(
          &whh[(size_t)(g * HID + u0 + lr) * HID + w * 256 + kk * 32 + lh * 8]);

  // --- cell ownership: thread -> (batch bi, unit ui); c in a register ---
  const int bi = tid >> 4, ui = tid & 15;
  const size_t ci = (size_t)(b0 + bi) * HID + u0 + ui;
  float c_reg = (t0 == 0) ? c0[ci] : c_ws[ci];

  for (int tl = 0; tl < tc; ++tl) {
    const int t = t0 + tl;
    const unsigned short* hin = (t & 1) ? hbf1 : hbf0;
    unsigned short* hout      = (t & 1) ? hbf0 : hbf1;

    // prefetch gin for this thread's cell (independent of h)
    float gi[4];
#pragma unroll
    for (int g = 0; g < 4; ++g)
      gi[g] = gin[((size_t)tl * BB + b0 + bi) * G4 + g * HID + u0 + ui];

    // A-fragments of h (this wave's K-slice)
    bf16x8 af[8];
#pragma unroll
    for (int kk = 0; kk < 8; ++kk)
      af[kk] = *reinterpret_cast<const bf16x8*>(
          &hin[(size_t)(b0 + lr) * HID + w * 256 + kk * 32 + lh * 8]);

    f32x4 acc[4];
#pragma unroll
    for (int g = 0; g < 4; ++g) acc[g] = (f32x4)0.f;
#pragma unroll
    for (int kk = 0; kk < 8; ++kk)
#pragma unroll
      for (int g = 0; g < 4; ++g)
        acc[g] = __builtin_amdgcn_mfma_f32_16x16x32_bf16(af[kk], bf[g][kk], acc[g], 0, 0, 0);

#pragma unroll
    for (int g = 0; g < 4; ++g)
#pragma unroll
      for (int r = 0; r < 4; ++r)
        red[w][g][lh * 4 + r][lr] = acc[g][r];
    __syncthreads();

    float gates[4];
#pragma unroll
    for (int g = 0; g < 4; ++g)
      gates[g] = red[0][g][bi][ui] + red[1][g][bi][ui] +
                 red[2][g][bi][ui] + red[3][g][bi][ui] + gi[g];

    float iv = 1.f / (1.f + expf(-gates[0]));
    float fv = 1.f / (1.f + expf(-gates[1]));
    float gv = tanhf(gates[2]);
    float ov = 1.f / (1.f + expf(-gates[3]));
    c_reg = fv * c_reg + iv * gv;
    float hn = ov * tanhf(c_reg);

    hout[ci] = f2bf(hn);
    out[((size_t)(b0 + bi) * NSTEP + t) * HID + u0 + ui] = hn;
    if (t == NSTEP - 1) {
      size_t tail = (size_t)BB * NSTEP * HID;
      out[tail + ci] = hn;                       // h_n
      out[tail + (size_t)BB * HID + ci] = c_reg; // c_n
    }

    grid.sync();
  }
  c_ws[ci] = c_reg;
}

// ---------------------------------------------------------------------------
extern "C" void kernel_launch(void* const* d_in, const int* in_sizes, int n_in,
                              void* d_out, int out_size, void* d_ws, size_t ws_size,
                              hipStream_t stream)
{
  const int*   tgt  = (const int*)d_in[0];
  const float* h0   = (const float*)d_in[1];
  const float* c0   = (const float*)d_in[2];
  const float* emb  = (const float*)d_in[5];
  const float* w_ih = (const float*)d_in[6];
  const float* w_hh = (const float*)d_in[7];
  const float* b_ih = (const float*)d_in[8];
  const float* b_hh = (const float*)d_in[9];
  float* out = (float*)d_out;

  char* p = (char*)d_ws;
  unsigned short* wih_bf = (unsigned short*)p; p += (size_t)G4 * HID * 2;
  unsigned short* whh_bf = (unsigned short*)p; p += (size_t)G4 * HID * 2;
  float*          bias   = (float*)p;          p += (size_t)G4 * 4;
  unsigned short* hbf0   = (unsigned short*)p; p += (size_t)BB * HID * 2;
  unsigned short* hbf1   = (unsigned short*)p; p += (size_t)BB * HID * 2;
  float*          c_ws   = (float*)p;          p += (size_t)BB * HID * 4;

  size_t fixed = (size_t)(p - (char*)d_ws);
  size_t rem = (ws_size > fixed) ? ws_size - fixed : 0;
  int Tc = (int)((rem > 262144 ? rem - 262144 : 0) / 1179648);
  if (Tc > NSTEP) Tc = NSTEP;
  if (Tc < 1) return;

  int MtMax = ((Tc * BB + 127) / 128) * 128;
  unsigned short* A_bf = (unsigned short*)p; p += (size_t)MtMax * HID * 2;
  float*          gin  = (float*)p;

  conv_f32_bf16<<<dim3((G4 * HID) / 8 / 256), 256, 0, stream>>>(w_ih, wih_bf, G4 * HID);
  conv_f32_bf16<<<dim3((G4 * HID) / 8 / 256), 256, 0, stream>>>(w_hh, whh_bf, G4 * HID);
  bias_add<<<dim3(G4 / 256), 256, 0, stream>>>(b_ih, b_hh, bias);
  conv_f32_bf16<<<dim3((BB * HID) / 8 / 256), 256, 0, stream>>>(h0, hbf0, BB * HID);

  for (int t0 = 0; t0 < NSTEP; t0 += Tc) {
    int tc = (NSTEP - t0 < Tc) ? (NSTEP - t0) : Tc;
    int Mt = ((tc * BB + 127) / 128) * 128;
    conv_A<<<dim3(Mt / 2), 256, 0, stream>>>(tgt, emb, A_bf, t0, tc);
    gin_mfma<<<dim3(Mt / 128, G4 / 128), 256, 0, stream>>>(A_bf, wih_bf, bias, gin, tc * BB);

    void* kargs[] = { (void*)&whh_bf, (void*)&gin, (void*)&hbf0, (void*)&hbf1,
                      (void*)&c_ws, (void*)&c0, (void*)&out, (void*)&t0, (void*)&tc };
    hipLaunchCooperativeKernel((void*)lstm_persist, dim3(256), dim3(256),
                               kargs, 0, stream);
  }
}

// Round 4
// 2675.893 us; speedup vs baseline: 1.5315x; 1.5315x over previous
//
#include <hip/hip_runtime.h>
#include <cstdint>
#include <cstddef>

#define HID   1024
#define G4    4096
#define BB    64
#define TSEQ  128
#define NSTEP 127
#define AGT   __HIP_MEMORY_SCOPE_AGENT

typedef __attribute__((ext_vector_type(4))) float f32x4;
typedef __attribute__((ext_vector_type(8))) short bf16x8;

__device__ __forceinline__ unsigned short f2bf(float x) {
  union { float f; unsigned u; } v; v.f = x;
  unsigned r = v.u + 0x7FFF + ((v.u >> 16) & 1);   // RNE
  return (unsigned short)(r >> 16);
}

// ---------------------------------------------------------------------------
__global__ __launch_bounds__(256) void conv_f32_bf16(
    const float* __restrict__ in, unsigned short* __restrict__ out, int n)
{
  int i = (blockIdx.x * 256 + threadIdx.x) * 8;
  if (i >= n) return;
  float4 v0 = *reinterpret_cast<const float4*>(&in[i]);
  float4 v1 = *reinterpret_cast<const float4*>(&in[i + 4]);
  unsigned short u[8];
  u[0] = f2bf(v0.x); u[1] = f2bf(v0.y); u[2] = f2bf(v0.z); u[3] = f2bf(v0.w);
  u[4] = f2bf(v1.x); u[5] = f2bf(v1.y); u[6] = f2bf(v1.z); u[7] = f2bf(v1.w);
  *reinterpret_cast<bf16x8*>(&out[i]) = *reinterpret_cast<bf16x8*>(u);
}

__global__ __launch_bounds__(256) void bias_add(
    const float* __restrict__ b_ih, const float* __restrict__ b_hh,
    float* __restrict__ bias)
{
  int i = blockIdx.x * 256 + threadIdx.x;
  if (i < G4) bias[i] = b_ih[i] + b_hh[i];
}

__global__ __launch_bounds__(256) void zero_cnt(unsigned int* __restrict__ cnt, int n)
{
  int i = blockIdx.x * 256 + threadIdx.x;
  if (i < n) cnt[i] = 0;
}

// ---------------------------------------------------------------------------
// Gather embedding rows for steps [t0, t0+tc) -> bf16 A [Mt][HID].
// ---------------------------------------------------------------------------
__global__ __launch_bounds__(256) void conv_A(
    const int* __restrict__ tgt, const float* __restrict__ emb,
    unsigned short* __restrict__ A, int t0, int tc)
{
  int i = blockIdx.x * 256 + threadIdx.x;
  int m  = i >> 7;
  int k8 = (i & 127) * 8;
  int tl = m >> 6, b = m & 63;
  float4 v0 = make_float4(0.f, 0.f, 0.f, 0.f), v1 = v0;
  if (tl < tc) {
    int tok = tgt[b * TSEQ + t0 + tl];
    if (tok != 0) {
      const float* src = &emb[(size_t)tok * HID + k8];
      v0 = *reinterpret_cast<const float4*>(src);
      v1 = *reinterpret_cast<const float4*>(src + 4);
    }
  }
  unsigned short u[8];
  u[0] = f2bf(v0.x); u[1] = f2bf(v0.y); u[2] = f2bf(v0.z); u[3] = f2bf(v0.w);
  u[4] = f2bf(v1.x); u[5] = f2bf(v1.y); u[6] = f2bf(v1.z); u[7] = f2bf(v1.w);
  *reinterpret_cast<bf16x8*>(&A[(size_t)m * HID + k8]) = *reinterpret_cast<bf16x8*>(u);
}

// ---------------------------------------------------------------------------
// Input GEMM, bf16 MFMA 16x16x32 (verified in R2).
// ---------------------------------------------------------------------------
__global__ __launch_bounds__(256) void gin_mfma(
    const unsigned short* __restrict__ A, const unsigned short* __restrict__ W,
    const float* __restrict__ bias, float* __restrict__ gin, int Mvalid)
{
  __shared__ unsigned short As[128 * 40];
  __shared__ unsigned short Bs[128 * 40];

  const int tid = threadIdx.x;
  const int m0 = blockIdx.x * 128, n0 = blockIdx.y * 128;
  const int l  = tid & 63, w = tid >> 6;
  const int wr = w >> 1, wc = w & 1;
  const int lr = l & 15, lh = l >> 4;

  f32x4 acc[4][4];
#pragma unroll
  for (int i = 0; i < 4; ++i)
#pragma unroll
    for (int j = 0; j < 4; ++j) acc[i][j] = (f32x4)0.f;

  for (int kc = 0; kc < HID; kc += 32) {
#pragma unroll
    for (int it = 0; it < 2; ++it) {
      int c = tid + it * 256;
      int row = c >> 2, k8 = (c & 3) * 8;
      *reinterpret_cast<bf16x8*>(&As[row * 40 + k8]) =
          *reinterpret_cast<const bf16x8*>(&A[(size_t)(m0 + row) * HID + kc + k8]);
      *reinterpret_cast<bf16x8*>(&Bs[row * 40 + k8]) =
          *reinterpret_cast<const bf16x8*>(&W[(size_t)(n0 + row) * HID + kc + k8]);
    }
    __syncthreads();

    bf16x8 af[4], bfr[4];
#pragma unroll
    for (int i = 0; i < 4; ++i) {
      af[i]  = *reinterpret_cast<const bf16x8*>(&As[(wr * 64 + i * 16 + lr) * 40 + lh * 8]);
      bfr[i] = *reinterpret_cast<const bf16x8*>(&Bs[(wc * 64 + i * 16 + lr) * 40 + lh * 8]);
    }
#pragma unroll
    for (int i = 0; i < 4; ++i)
#pragma unroll
      for (int j = 0; j < 4; ++j)
        acc[i][j] = __builtin_amdgcn_mfma_f32_16x16x32_bf16(af[i], bfr[j], acc[i][j], 0, 0, 0);
    __syncthreads();
  }

#pragma unroll
  for (int j = 0; j < 4; ++j) {
    int n = n0 + wc * 64 + j * 16 + lr;
    float bn = bias[n];
#pragma unroll
    for (int i = 0; i < 4; ++i) {
      int mb = m0 + wr * 64 + i * 16 + lh * 4;
#pragma unroll
      for (int r = 0; r < 4; ++r) {
        int m = mb + r;
        if (m < Mvalid) gin[(size_t)m * G4 + n] = acc[i][j][r] + bn;
      }
    }
  }
}

// ---------------------------------------------------------------------------
// Persistent LSTM, custom agent-scope barrier (no cg::grid.sync, no L2 flush
// storms). 256 blocks = 4 batch-groups (16 batches) x 64 unit-blocks
// (16 units). Batches never communicate across groups. Per step, per group:
// blocks MFMA their gate slice (w_hh pinned in VGPRs), exchange h via
// agent-scope (L3-coherent) atomics, arrive on a per-step L3 counter.
// ---------------------------------------------------------------------------
__global__ __launch_bounds__(256, 1) void lstm_persist(
    const unsigned short* __restrict__ whh, const float* __restrict__ gin,
    unsigned int* __restrict__ hb0, unsigned int* __restrict__ hb1,
    float* __restrict__ c_ws, const float* __restrict__ c0,
    float* __restrict__ out, unsigned int* __restrict__ cnt,
    int t0, int tc)
{
  __shared__ float red[4][4][16][16];   // [wave][gate][batch][unit]

  const int tid = threadIdx.x;
  const int l = tid & 63, w = tid >> 6;
  const int lr = l & 15, lh = l >> 4;
  const int grp = blockIdx.x >> 6;      // batch group [0,4)
  const int ub  = blockIdx.x & 63;      // unit block  [0,64)
  const int b0 = grp * 16;
  const int u0 = ub * 16;

  // --- w_hh fragments -> VGPRs, pinned against rematerialization ---
  bf16x8 bw[4][8];
#pragma unroll
  for (int g = 0; g < 4; ++g)
#pragma unroll
    for (int kk = 0; kk < 8; ++kk) {
      bw[g][kk] = *reinterpret_cast<const bf16x8*>(
          &whh[(size_t)(g * HID + u0 + lr) * HID + w * 256 + kk * 32 + lh * 8]);
      asm volatile("" : "+v"(bw[g][kk]));
    }

  const int bi = tid >> 4, ui = tid & 15;
  const size_t ci = (size_t)(b0 + bi) * HID + u0 + ui;
  float c_reg = (t0 == 0) ? c0[ci] : c_ws[ci];

  unsigned int* cgrp = cnt + grp * NSTEP;

  for (int tl = 0; tl < tc; ++tl) {
    const int t = t0 + tl;
    const unsigned int* hin = (t & 1) ? hb1 : hb0;
    unsigned int*       hout = (t & 1) ? hb0 : hb1;

    // gin prefetch (independent of h)
    float gi[4];
#pragma unroll
    for (int g = 0; g < 4; ++g)
      gi[g] = gin[((size_t)tl * BB + b0 + bi) * G4 + g * HID + u0 + ui];

    // wait for h_t (all 64 blocks of this group produced their slice)
    if (t > 0) {
      while (__hip_atomic_load(&cgrp[t - 1], __ATOMIC_RELAXED, AGT) < 64u)
        __builtin_amdgcn_s_sleep(1);
      __builtin_amdgcn_fence(__ATOMIC_ACQUIRE, "agent");
    }

    // A-fragments of h_t via agent-scope (L2-bypassing) loads
    bf16x8 af[8];
#pragma unroll
    for (int kk = 0; kk < 8; ++kk) {
      size_t base = ((size_t)(b0 + lr) * HID + (size_t)w * 256 + kk * 32 + lh * 8) >> 1;
      unsigned long long lo = __hip_atomic_load(
          reinterpret_cast<const unsigned long long*>(&hin[base]), __ATOMIC_RELAXED, AGT);
      unsigned long long hi = __hip_atomic_load(
          reinterpret_cast<const unsigned long long*>(&hin[base + 2]), __ATOMIC_RELAXED, AGT);
      union { unsigned long long q[2]; bf16x8 v; } u;
      u.q[0] = lo; u.q[1] = hi;
      af[kk] = u.v;
    }

    f32x4 acc[4];
#pragma unroll
    for (int g = 0; g < 4; ++g) acc[g] = (f32x4)0.f;
#pragma unroll
    for (int kk = 0; kk < 8; ++kk)
#pragma unroll
      for (int g = 0; g < 4; ++g)
        acc[g] = __builtin_amdgcn_mfma_f32_16x16x32_bf16(af[kk], bw[g][kk], acc[g], 0, 0, 0);

#pragma unroll
    for (int g = 0; g < 4; ++g)
#pragma unroll
      for (int r = 0; r < 4; ++r)
        red[w][g][lh * 4 + r][lr] = acc[g][r];
    __syncthreads();

    float gates[4];
#pragma unroll
    for (int g = 0; g < 4; ++g)
      gates[g] = red[0][g][bi][ui] + red[1][g][bi][ui] +
                 red[2][g][bi][ui] + red[3][g][bi][ui] + gi[g];

    float iv = 1.f / (1.f + expf(-gates[0]));
    float fv = 1.f / (1.f + expf(-gates[1]));
    float gv = tanhf(gates[2]);
    float ov = 1.f / (1.f + expf(-gates[3]));
    c_reg = fv * c_reg + iv * gv;
    float hn = ov * tanhf(c_reg);

    // publish h_{t+1}: pack bf16 pair via lane partner, agent-scope store
    unsigned hv = (unsigned)f2bf(hn);
    unsigned pv = (unsigned)__shfl_xor((int)hv, 1);
    if ((tid & 1) == 0) {
      unsigned word = (hv & 0xffffu) | (pv << 16);
      __hip_atomic_store(&hout[ci >> 1], word, __ATOMIC_RELAXED, AGT);
    }

    out[((size_t)(b0 + bi) * NSTEP + t) * HID + u0 + ui] = hn;
    if (t == NSTEP - 1) {
      size_t tail = (size_t)BB * NSTEP * HID;
      out[tail + ci] = hn;                        // h_n
      out[tail + (size_t)BB * HID + ci] = c_reg;  // c_n
    }

    // drain all threads' stores (syncthreads waits vmcnt), then arrive
    __syncthreads();
    if (tid == 0)
      __hip_atomic_fetch_add(&cgrp[t], 1u, __ATOMIC_RELEASE, AGT);
  }
  c_ws[ci] = c_reg;
}

// ---------------------------------------------------------------------------
extern "C" void kernel_launch(void* const* d_in, const int* in_sizes, int n_in,
                              void* d_out, int out_size, void* d_ws, size_t ws_size,
                              hipStream_t stream)
{
  const int*   tgt  = (const int*)d_in[0];
  const float* h0   = (const float*)d_in[1];
  const float* c0   = (const float*)d_in[2];
  const float* emb  = (const float*)d_in[5];
  const float* w_ih = (const float*)d_in[6];
  const float* w_hh = (const float*)d_in[7];
  const float* b_ih = (const float*)d_in[8];
  const float* b_hh = (const float*)d_in[9];
  float* out = (float*)d_out;

  char* p = (char*)d_ws;
  unsigned short* wih_bf = (unsigned short*)p; p += (size_t)G4 * HID * 2;
  unsigned short* whh_bf = (unsigned short*)p; p += (size_t)G4 * HID * 2;
  float*          bias   = (float*)p;          p += (size_t)G4 * 4;
  unsigned int*   hb0    = (unsigned int*)p;   p += (size_t)BB * HID * 2;
  unsigned int*   hb1    = (unsigned int*)p;   p += (size_t)BB * HID * 2;
  float*          c_ws   = (float*)p;          p += (size_t)BB * HID * 4;
  unsigned int*   cnt    = (unsigned int*)p;   p += (size_t)4 * NSTEP * 4 + 64;

  size_t fixed = (size_t)(p - (char*)d_ws);
  size_t rem = (ws_size > fixed) ? ws_size - fixed : 0;
  int Tc = (int)((rem > 262144 ? rem - 262144 : 0) / 1179648);
  if (Tc > NSTEP) Tc = NSTEP;
  if (Tc < 1) return;

  int MtMax = ((Tc * BB + 127) / 128) * 128;
  unsigned short* A_bf = (unsigned short*)p; p += (size_t)MtMax * HID * 2;
  float*          gin  = (float*)p;

  conv_f32_bf16<<<dim3((G4 * HID) / 8 / 256), 256, 0, stream>>>(w_ih, wih_bf, G4 * HID);
  conv_f32_bf16<<<dim3((G4 * HID) / 8 / 256), 256, 0, stream>>>(w_hh, whh_bf, G4 * HID);
  bias_add<<<dim3(G4 / 256), 256, 0, stream>>>(b_ih, b_hh, bias);
  conv_f32_bf16<<<dim3((BB * HID) / 8 / 256), 256, 0, stream>>>(h0, (unsigned short*)hb0, BB * HID);
  zero_cnt<<<dim3(2), 256, 0, stream>>>(cnt, 4 * NSTEP);

  for (int t0 = 0; t0 < NSTEP; t0 += Tc) {
    int tc = (NSTEP - t0 < Tc) ? (NSTEP - t0) : Tc;
    int Mt = ((tc * BB + 127) / 128) * 128;
    conv_A<<<dim3(Mt / 2), 256, 0, stream>>>(tgt, emb, A_bf, t0, tc);
    gin_mfma<<<dim3(Mt / 128, G4 / 128), 256, 0, stream>>>(A_bf, wih_bf, bias, gin, tc * BB);

    void* kargs[] = { (void*)&whh_bf, (void*)&gin, (void*)&hb0, (void*)&hb1,
                      (void*)&c_ws, (void*)&c0, (void*)&out, (void*)&cnt,
                      (void*)&t0, (void*)&tc };
    hipLaunchCooperativeKernel((void*)lstm_persist, dim3(256), dim3(256),
                               kargs, 0, stream);
  }
}

// Round 5
// 609.509 us; speedup vs baseline: 6.7236x; 4.3902x over previous
//
#include <hip/hip_runtime.h>
#include <cstdint>
#include <cstddef>

#define HID   1024
#define G4    4096
#define BB    64
#define TSEQ  128
#define NSTEP 127
#define AGT   __HIP_MEMORY_SCOPE_AGENT

typedef __attribute__((ext_vector_type(4))) float f32x4;
typedef __attribute__((ext_vector_type(8))) short bf16x8;

__device__ __forceinline__ unsigned short f2bf(float x) {
  union { float f; unsigned u; } v; v.f = x;
  unsigned r = v.u + 0x7FFF + ((v.u >> 16) & 1);   // RNE
  return (unsigned short)(r >> 16);
}

// ---------------------------------------------------------------------------
__global__ __launch_bounds__(256) void conv_f32_bf16(
    const float* __restrict__ in, unsigned short* __restrict__ out, int n)
{
  int i = (blockIdx.x * 256 + threadIdx.x) * 8;
  if (i >= n) return;
  float4 v0 = *reinterpret_cast<const float4*>(&in[i]);
  float4 v1 = *reinterpret_cast<const float4*>(&in[i + 4]);
  unsigned short u[8];
  u[0] = f2bf(v0.x); u[1] = f2bf(v0.y); u[2] = f2bf(v0.z); u[3] = f2bf(v0.w);
  u[4] = f2bf(v1.x); u[5] = f2bf(v1.y); u[6] = f2bf(v1.z); u[7] = f2bf(v1.w);
  *reinterpret_cast<bf16x8*>(&out[i]) = *reinterpret_cast<bf16x8*>(u);
}

__global__ __launch_bounds__(256) void bias_add(
    const float* __restrict__ b_ih, const float* __restrict__ b_hh,
    float* __restrict__ bias)
{
  int i = blockIdx.x * 256 + threadIdx.x;
  if (i < G4) bias[i] = b_ih[i] + b_hh[i];
}

// ---------------------------------------------------------------------------
// Gather embedding rows for steps [t0, t0+tc) -> bf16 A [Mt][HID].
// ---------------------------------------------------------------------------
__global__ __launch_bounds__(256) void conv_A(
    const int* __restrict__ tgt, const float* __restrict__ emb,
    unsigned short* __restrict__ A, int t0, int tc)
{
  int i = blockIdx.x * 256 + threadIdx.x;
  int m  = i >> 7;
  int k8 = (i & 127) * 8;
  int tl = m >> 6, b = m & 63;
  float4 v0 = make_float4(0.f, 0.f, 0.f, 0.f), v1 = v0;
  if (tl < tc) {
    int tok = tgt[b * TSEQ + t0 + tl];
    if (tok != 0) {
      const float* src = &emb[(size_t)tok * HID + k8];
      v0 = *reinterpret_cast<const float4*>(src);
      v1 = *reinterpret_cast<const float4*>(src + 4);
    }
  }
  unsigned short u[8];
  u[0] = f2bf(v0.x); u[1] = f2bf(v0.y); u[2] = f2bf(v0.z); u[3] = f2bf(v0.w);
  u[4] = f2bf(v1.x); u[5] = f2bf(v1.y); u[6] = f2bf(v1.z); u[7] = f2bf(v1.w);
  *reinterpret_cast<bf16x8*>(&A[(size_t)m * HID + k8]) = *reinterpret_cast<bf16x8*>(u);
}

// ---------------------------------------------------------------------------
// Input GEMM, bf16 MFMA 16x16x32 (verified in R2).
// ---------------------------------------------------------------------------
__global__ __launch_bounds__(256) void gin_mfma(
    const unsigned short* __restrict__ A, const unsigned short* __restrict__ W,
    const float* __restrict__ bias, float* __restrict__ gin, int Mvalid)
{
  __shared__ unsigned short As[128 * 40];
  __shared__ unsigned short Bs[128 * 40];

  const int tid = threadIdx.x;
  const int m0 = blockIdx.x * 128, n0 = blockIdx.y * 128;
  const int l  = tid & 63, w = tid >> 6;
  const int wr = w >> 1, wc = w & 1;
  const int lr = l & 15, lh = l >> 4;

  f32x4 acc[4][4];
#pragma unroll
  for (int i = 0; i < 4; ++i)
#pragma unroll
    for (int j = 0; j < 4; ++j) acc[i][j] = (f32x4)0.f;

  for (int kc = 0; kc < HID; kc += 32) {
#pragma unroll
    for (int it = 0; it < 2; ++it) {
      int c = tid + it * 256;
      int row = c >> 2, k8 = (c & 3) * 8;
      *reinterpret_cast<bf16x8*>(&As[row * 40 + k8]) =
          *reinterpret_cast<const bf16x8*>(&A[(size_t)(m0 + row) * HID + kc + k8]);
      *reinterpret_cast<bf16x8*>(&Bs[row * 40 + k8]) =
          *reinterpret_cast<const bf16x8*>(&W[(size_t)(n0 + row) * HID + kc + k8]);
    }
    __syncthreads();

    bf16x8 af[4], bfr[4];
#pragma unroll
    for (int i = 0; i < 4; ++i) {
      af[i]  = *reinterpret_cast<const bf16x8*>(&As[(wr * 64 + i * 16 + lr) * 40 + lh * 8]);
      bfr[i] = *reinterpret_cast<const bf16x8*>(&Bs[(wc * 64 + i * 16 + lr) * 40 + lh * 8]);
    }
#pragma unroll
    for (int i = 0; i < 4; ++i)
#pragma unroll
      for (int j = 0; j < 4; ++j)
        acc[i][j] = __builtin_amdgcn_mfma_f32_16x16x32_bf16(af[i], bfr[j], acc[i][j], 0, 0, 0);
    __syncthreads();
  }

#pragma unroll
  for (int j = 0; j < 4; ++j) {
    int n = n0 + wc * 64 + j * 16 + lr;
    float bn = bias[n];
#pragma unroll
    for (int i = 0; i < 4; ++i) {
      int mb = m0 + wr * 64 + i * 16 + lh * 4;
#pragma unroll
      for (int r = 0; r < 4; ++r) {
        int m = mb + r;
        if (m < Mvalid) gin[(size_t)m * G4 + n] = acc[i][j][r] + bn;
      }
    }
  }
}

// ---------------------------------------------------------------------------
// Persistent LSTM, fence-free agent-scope synchronization.
// 256 blocks = 4 batch-groups x 64 unit-blocks. All h traffic flows through
// relaxed agent-scope (sc1, L3-direct) atomics, so no cache fences are ever
// required. Producer arrival = ONE flag store per block (after __syncthreads
// drains vmcnt). Consumers poll 64 flags in parallel (lane l -> flag l).
// w_hh fragments pinned in VGPRs via in-loop asm. c stays in a register.
// ---------------------------------------------------------------------------
__global__ __launch_bounds__(256, 1) void lstm_persist(
    const unsigned short* __restrict__ whh, const float* __restrict__ gin,
    unsigned int* __restrict__ hb0, unsigned int* __restrict__ hb1,
    float* __restrict__ c_ws, const float* __restrict__ c0,
    float* __restrict__ out, unsigned int* __restrict__ flags,
    int t0, int tc)
{
  __shared__ float red[4][4][16][16];   // [wave][gate][batch][unit]

  const int tid = threadIdx.x;
  const int l = tid & 63, w = tid >> 6;
  const int lr = l & 15, lh = l >> 4;
  const int grp = blockIdx.x >> 6;      // batch group [0,4)
  const int ub  = blockIdx.x & 63;      // unit block  [0,64)
  const int b0 = grp * 16;
  const int u0 = ub * 16;

  // --- w_hh fragments -> VGPRs (loaded once, pinned in the loop) ---
  bf16x8 bw[4][8];
#pragma unroll
  for (int g = 0; g < 4; ++g)
#pragma unroll
    for (int kk = 0; kk < 8; ++kk)
      bw[g][kk] = *reinterpret_cast<const bf16x8*>(
          &whh[(size_t)(g * HID + u0 + lr) * HID + w * 256 + kk * 32 + lh * 8]);

  const int bi = tid >> 4, ui = tid & 15;
  const size_t ci = (size_t)(b0 + bi) * HID + u0 + ui;
  float c_reg = (t0 == 0) ? c0[ci] : c_ws[ci];

  for (int tl = 0; tl < tc; ++tl) {
    const int t = t0 + tl;
    const unsigned int* hin  = (t & 1) ? hb1 : hb0;
    unsigned int*       hout = (t & 1) ? hb0 : hb1;

    // keep weights live across the loop (defeats remat; 0-cost)
#pragma unroll
    for (int g = 0; g < 4; ++g)
#pragma unroll
      for (int kk = 0; kk < 8; ++kk)
        asm volatile("" : "+v"(bw[g][kk]));

    // gin prefetch (independent of h; overlaps with the poll below)
    float gi[4];
#pragma unroll
    for (int g = 0; g < 4; ++g)
      gi[g] = gin[((size_t)tl * BB + b0 + bi) * G4 + g * HID + u0 + ui];

    // wait for h_t: poll the 64 per-block flags of this group in parallel
    if (t > 0) {
      const unsigned int* fl = flags + (((size_t)(t - 1) * 4 + grp) * 64 + l) * 4;
      while (true) {
        unsigned v = __hip_atomic_load(fl, __ATOMIC_RELAXED, AGT);
        if (__all(v != 0)) break;
        __builtin_amdgcn_s_sleep(2);
      }
    }

    // A-fragments of h_t via agent-scope (L3-direct) loads
    bf16x8 af[8];
#pragma unroll
    for (int kk = 0; kk < 8; ++kk) {
      size_t base = ((size_t)(b0 + lr) * HID + (size_t)w * 256 + kk * 32 + lh * 8) >> 1;
      unsigned long long lo = __hip_atomic_load(
          reinterpret_cast<const unsigned long long*>(&hin[base]), __ATOMIC_RELAXED, AGT);
      unsigned long long hi = __hip_atomic_load(
          reinterpret_cast<const unsigned long long*>(&hin[base + 2]), __ATOMIC_RELAXED, AGT);
      union { unsigned long long q[2]; bf16x8 v; } u;
      u.q[0] = lo; u.q[1] = hi;
      af[kk] = u.v;
    }

    f32x4 acc[4];
#pragma unroll
    for (int g = 0; g < 4; ++g) acc[g] = (f32x4)0.f;
#pragma unroll
    for (int kk = 0; kk < 8; ++kk)
#pragma unroll
      for (int g = 0; g < 4; ++g)
        acc[g] = __builtin_amdgcn_mfma_f32_16x16x32_bf16(af[kk], bw[g][kk], acc[g], 0, 0, 0);

#pragma unroll
    for (int g = 0; g < 4; ++g)
#pragma unroll
      for (int r = 0; r < 4; ++r)
        red[w][g][lh * 4 + r][lr] = acc[g][r];
    __syncthreads();

    float gates[4];
#pragma unroll
    for (int g = 0; g < 4; ++g)
      gates[g] = red[0][g][bi][ui] + red[1][g][bi][ui] +
                 red[2][g][bi][ui] + red[3][g][bi][ui] + gi[g];

    float iv = 1.f / (1.f + expf(-gates[0]));
    float fv = 1.f / (1.f + expf(-gates[1]));
    float gv = tanhf(gates[2]);
    float ov = 1.f / (1.f + expf(-gates[3]));
    c_reg = fv * c_reg + iv * gv;
    float hn = ov * tanhf(c_reg);

    // publish h_{t+1}: pack bf16 pair via lane partner, L3-direct store
    unsigned hv = (unsigned)f2bf(hn);
    unsigned pv = (unsigned)__shfl_xor((int)hv, 1);
    if ((tid & 1) == 0) {
      unsigned word = (hv & 0xffffu) | (pv << 16);
      __hip_atomic_store(&hout[ci >> 1], word, __ATOMIC_RELAXED, AGT);
    }

    out[((size_t)(b0 + bi) * NSTEP + t) * HID + u0 + ui] = hn;
    if (t == NSTEP - 1) {
      size_t tail = (size_t)BB * NSTEP * HID;
      out[tail + ci] = hn;                        // h_n
      out[tail + (size_t)BB * HID + ci] = c_reg;  // c_n
    }

    // __syncthreads emits s_waitcnt vmcnt(0) before s_barrier -> all h
    // stores of this block are L3-acked; then a single relaxed flag store.
    __syncthreads();
    if (tid == 0)
      __hip_atomic_store(&flags[(((size_t)t * 4 + grp) * 64 + ub) * 4], 1u,
                         __ATOMIC_RELAXED, AGT);
  }
  c_ws[ci] = c_reg;
}

// ---------------------------------------------------------------------------
extern "C" void kernel_launch(void* const* d_in, const int* in_sizes, int n_in,
                              void* d_out, int out_size, void* d_ws, size_t ws_size,
                              hipStream_t stream)
{
  const int*   tgt  = (const int*)d_in[0];
  const float* h0   = (const float*)d_in[1];
  const float* c0   = (const float*)d_in[2];
  const float* emb  = (const float*)d_in[5];
  const float* w_ih = (const float*)d_in[6];
  const float* w_hh = (const float*)d_in[7];
  const float* b_ih = (const float*)d_in[8];
  const float* b_hh = (const float*)d_in[9];
  float* out = (float*)d_out;

  const size_t FLAGS_BYTES = (size_t)NSTEP * 4 * 64 * 16;   // t x grp x ub, 16B pad

  char* p = (char*)d_ws;
  unsigned short* wih_bf = (unsigned short*)p; p += (size_t)G4 * HID * 2;
  unsigned short* whh_bf = (unsigned short*)p; p += (size_t)G4 * HID * 2;
  float*          bias   = (float*)p;          p += (size_t)G4 * 4;
  unsigned int*   hb0    = (unsigned int*)p;   p += (size_t)BB * HID * 2;
  unsigned int*   hb1    = (unsigned int*)p;   p += (size_t)BB * HID * 2;
  float*          c_ws   = (float*)p;          p += (size_t)BB * HID * 4;
  unsigned int*   flags  = (unsigned int*)p;   p += FLAGS_BYTES;

  size_t fixed = (size_t)(p - (char*)d_ws);
  size_t rem = (ws_size > fixed) ? ws_size - fixed : 0;
  int Tc = (int)((rem > 262144 ? rem - 262144 : 0) / 1179648);
  if (Tc > NSTEP) Tc = NSTEP;
  if (Tc < 1) return;

  int MtMax = ((Tc * BB + 127) / 128) * 128;
  unsigned short* A_bf = (unsigned short*)p; p += (size_t)MtMax * HID * 2;
  float*          gin  = (float*)p;

  hipMemsetAsync(flags, 0, FLAGS_BYTES, stream);
  conv_f32_bf16<<<dim3((G4 * HID) / 8 / 256), 256, 0, stream>>>(w_ih, wih_bf, G4 * HID);
  conv_f32_bf16<<<dim3((G4 * HID) / 8 / 256), 256, 0, stream>>>(w_hh, whh_bf, G4 * HID);
  bias_add<<<dim3(G4 / 256), 256, 0, stream>>>(b_ih, b_hh, bias);
  conv_f32_bf16<<<dim3((BB * HID) / 8 / 256), 256, 0, stream>>>(h0, (unsigned short*)hb0, BB * HID);

  for (int t0 = 0; t0 < NSTEP; t0 += Tc) {
    int tc = (NSTEP - t0 < Tc) ? (NSTEP - t0) : Tc;
    int Mt = ((tc * BB + 127) / 128) * 128;
    conv_A<<<dim3(Mt / 2), 256, 0, stream>>>(tgt, emb, A_bf, t0, tc);
    gin_mfma<<<dim3(Mt / 128, G4 / 128), 256, 0, stream>>>(A_bf, wih_bf, bias, gin, tc * BB);

    void* kargs[] = { (void*)&whh_bf, (void*)&gin, (void*)&hb0, (void*)&hb1,
                      (void*)&c_ws, (void*)&c0, (void*)&out, (void*)&flags,
                      (void*)&t0, (void*)&tc };
    hipLaunchCooperativeKernel((void*)lstm_persist, dim3(256), dim3(256),
                               kargs, 0, stream);
  }
}